// Round 11
// baseline (1152.282 us; speedup 1.0000x reference)
//
#include <hip/hip_runtime.h>
#include <hip/hip_fp16.h>
#include <cmath>
#include <float.h>

// Problem constants
#define NUM_EMB 8192
#define DIM 256
#define HW 1024
#define N_TOK 32768
#define KSPLIT 4
#define KRANGE (NUM_EMB/KSPLIT)      // 2048 codes per split
#define OUT_ZQ_ELEMS 8388608

// coarse capture: G' = 8192 * z.e ; d-margin = 2*0.4/8192 = 9.8e-5 vs required
// cell(3.05e-5)+2*eps_fp16(2.6e-5) = 5.7e-5 -> 1.7x safety
// capture superset is safe (cut only ever lowered); CAP overflow falls back to
// exact full scan in vq_rg_kernel.
// R11: cycle audit of the ~725k cyc/CU invariant: MFMA 131k + DS(reads 196k +
// shuffles 146k + atomics) + VALU 230k ~= sum ~= observed -> pipes don't
// overlap at ~2 waves/SIMD; time = SUM of per-wave work. Fix shrinks the sum:
// 64-token waves (each B frag feeds 2 MFMAs: DS-reads halved, 2 indep acc
// chains = 2x MFMA ILP, addressing VALU halved) + reduce cadence 4->8 buffers.
#define CAP 24
#define MARGIN_GP 0.4f

// dist tiling: block = 256 tokens x KRANGE codes; LDS buffer = 32 codes (16KB)
#define BM 256
#define BCODES 32
#define NBUF (KRANGE/BCODES)         // 64 buffers per block

// ws layout (byte offsets)
#define WS_MSE    0
#define WS_COUNTS 64
#define WS_CNT    (WS_COUNTS + NUM_EMB*4)        // int[KSPLIT*N_TOK]
#define WS_MEMSET_END (WS_CNT + KSPLIT*N_TOK*4)
#define WS_Z2     WS_MEMSET_END                  // float[N_TOK]
#define WS_CANDI  (WS_Z2 + N_TOK*4)              // ushort[KSPLIT*N_TOK*CAP]

typedef _Float16 half8 __attribute__((ext_vector_type(8)));
typedef _Float16 half4v __attribute__((ext_vector_type(4)));
typedef float f32x16 __attribute__((ext_vector_type(16)));
typedef __attribute__((address_space(3))) void lds_void;
typedef __attribute__((address_space(1))) const void gbl_void;

// ---------------------------------------------------------------------------
// pack z -> fp16 token-major [n][c]  AND  z2[n] (numpy pairwise_sum(256)-exact)
__global__ __launch_bounds__(256) void vq_pack_z(
    const float* __restrict__ z, _Float16* __restrict__ zh, float* __restrict__ z2)
{
    __shared__ float zt[32][257];
    __shared__ float rr[32][16];
    int t = threadIdx.x;
    int n0 = blockIdx.x * 32;
    int b = n0 >> 10, hw0 = n0 & 1023;
    const float* zb = z + (size_t)b * DIM * HW + hw0;
    int tn = t & 31, tc = t >> 5;
    #pragma unroll 4
    for (int it = 0; it < 32; it++) {
        int c = it * 8 + tc;
        zt[tn][c] = zb[(size_t)c * HW + tn];
    }
    __syncthreads();
    int tn2 = t & 31, tj = t >> 5;
    #pragma unroll
    for (int h = 0; h < 2; h++) {
        float v0 = zt[tn2][h*128 + tj];
        float r = __fmul_rn(v0, v0);
        for (int i = 8; i < 128; i += 8) {
            float v = zt[tn2][h*128 + i + tj];
            r = __fadd_rn(r, __fmul_rn(v, v));
        }
        rr[tn2][h*8 + tj] = r;
    }
    int row = t >> 3, seg = t & 7;
    half8 outv[4];
    #pragma unroll
    for (int q = 0; q < 4; q++)
        #pragma unroll
        for (int u = 0; u < 8; u++)
            outv[q][u] = (_Float16)zt[row][seg*32 + q*8 + u];
    half8* dst = (half8*)(zh + (size_t)(n0 + row) * DIM + seg * 32);
    #pragma unroll
    for (int q = 0; q < 4; q++) dst[q] = outv[q];
    __syncthreads();
    if (t < 32) {
        const float* rw = rr[t];
        float h0 = __fadd_rn(__fadd_rn(__fadd_rn(rw[0], rw[1]), __fadd_rn(rw[2], rw[3])),
                             __fadd_rn(__fadd_rn(rw[4], rw[5]), __fadd_rn(rw[6], rw[7])));
        float h1 = __fadd_rn(__fadd_rn(__fadd_rn(rw[8], rw[9]), __fadd_rn(rw[10], rw[11])),
                             __fadd_rn(__fadd_rn(rw[12], rw[13]), __fadd_rn(rw[14], rw[15])));
        z2[n0 + t] = __fadd_rn(h0, h1);
    }
}

// pack e: fp32 -> fp16 prescaled by 8192 (exact pow2; avoids fp16 denormals)
__global__ __launch_bounds__(256) void vq_pack_e(
    const float* __restrict__ emb, _Float16* __restrict__ eh)
{
    int i = blockIdx.x * 256 + threadIdx.x;
    float4 v = ((const float4*)emb)[i];
    half4v h;
    h[0] = (_Float16)(v.x * 8192.0f);
    h[1] = (_Float16)(v.y * 8192.0f);
    h[2] = (_Float16)(v.z * 8192.0f);
    h[3] = (_Float16)(v.w * 8192.0f);
    *(half4v*)(eh + (size_t)i * 4) = h;
}

// ---------------------------------------------------------------------------
// fp16 MFMA coarse pass v10 (64-token waves = B-reuse x2):
//  - grid (128,4) = 512 blocks = 2 independent blocks/CU; 256 threads = 4
//    waves; wave w owns 64 tokens (2 rowgroups; A0/A1 = 128 VGPRs) and reads
//    all 32 codes of each buffer: each ds_read_b128 feeds TWO MFMAs into two
//    INDEPENDENT acc chains (2x ILP; DS-read bytes and addr VALU halved)
//  - B: 32-code buffers (16KB), double-buffered; 33KB LDS/block
//  - drain-synced staging (ONE __syncthreads per buffer; R2 lesson: keeps eh
//    L2-resident); global_load_lds 16B; rotate-by-code swizzle (0 conflicts)
//  - capture counters in LDS (R4); candi fire-and-forget; cnt flushed once;
//    lane-local running max + exact 32-lane reduce every 8th buffer
//    (256-code window, R7-validated cadence), warmup i<4
__global__ __launch_bounds__(256) void vq_dist_kernel(
    const _Float16* __restrict__ zh, const _Float16* __restrict__ eh,
    int* __restrict__ cnt, unsigned short* __restrict__ candi)
{
    __shared__ _Float16 Bs[2][8192];    // 2 x 16KB: 32 codes x 256 k, swizzled
    __shared__ int cntL[BM];            // per-token capture counter (LDS atomic)
    int t = threadIdx.x;
    int w = t >> 6, lane = t & 63;
    int lm = lane & 31, lh = lane >> 5;
    int n0 = blockIdx.x * BM;
    int ks = blockIdx.y;
    int kbase = ks * KRANGE;

    cntL[t] = 0;

    // A fragments: 64 tokens (2 rowgroups of 32), full K=256, zero LDS traffic
    const _Float16* arow = zh + (size_t)(n0 + w*64 + lm) * DIM + lh * 8;
    half8 A0[16], A1[16];
    #pragma unroll
    for (int s = 0; s < 16; s++) {
        A0[s] = *(const half8*)(arow + s * 16);
        A1[s] = *(const half8*)(arow + 32*DIM + s * 16);
    }

    // stage: chunk p = rr*256+t in [0,1024): code=p>>5 (32 codes), slot=p&31,
    // logical oct = ((p&31)-code)&31 (rotate-by-code; conflict-free b128 reads)
    auto STAGE = [&](int ii, int b) {
        int cb0 = kbase + ii * BCODES;
        #pragma unroll
        for (int rr = 0; rr < 4; rr++) {
            int p = rr * 256 + t;
            int cd = p >> 5;
            int oc = ((p & 31) - cd) & 31;
            __builtin_amdgcn_global_load_lds(
                (gbl_void*)(eh + (size_t)(cb0 + cd) * DIM + oc * 8),
                (lds_void*)((char*)&Bs[b][0] + p * 16), 16, 0, 0);
        }
    };

    // lane-local running max per (rowgroup, e); reduced cross-lane periodically
    float m0[16], m1[16];
    #pragma unroll
    for (int e = 0; e < 16; e++) { m0[e] = -1e30f; m1[e] = -1e30f; }

    int cl = lm;                         // this lane's code within 32-code buffer

    auto COMPUTE = [&](int i, int b) {
        const _Float16* Bb = &Bs[b][0] + (size_t)cl * 256;  // 32 octs * 8 halves
        f32x16 a0, a1;
        #pragma unroll
        for (int e = 0; e < 16; e++) { a0[e] = 0.f; a1[e] = 0.f; }

        __builtin_amdgcn_s_setprio(1);
        #pragma unroll
        for (int s = 0; s < 16; s++) {
            half8 bf = *(const half8*)(Bb + (((s*2 + lh) + cl) & 31) * 8);
            a0 = __builtin_amdgcn_mfma_f32_32x32x16_f16(A0[s], bf, a0, 0, 0, 0);
            a1 = __builtin_amdgcn_mfma_f32_32x32x16_f16(A1[s], bf, a1, 0, 0, 0);
        }
        __builtin_amdgcn_s_setprio(0);

        // lane-local max update
        #pragma unroll
        for (int e = 0; e < 16; e++) {
            m0[e] = fmaxf(m0[e], a0[e]);
            m1[e] = fmaxf(m1[e], a1[e]);
        }
        bool doRed = (i < 4) || ((i & 7) == 7);
        if (doRed) {  // exact row max across the 32 column-lanes (256-code window)
            #pragma unroll
            for (int e = 0; e < 16; e++) {
                float q0 = m0[e], q1 = m1[e];
                #pragma unroll
                for (int o = 1; o <= 16; o <<= 1) {
                    q0 = fmaxf(q0, __shfl_xor(q0, o));
                    q1 = fmaxf(q1, __shfl_xor(q1, o));
                }
                m0[e] = q0; m1[e] = q1;
            }
        }
        int cb = kbase + i * BCODES;
        #pragma unroll
        for (int e = 0; e < 16; e++) {
            int rowe = (e & 3) + 8 * (e >> 2) + 4 * lh;
            if (a0[e] > m0[e] - MARGIN_GP) {
                int tok = w * 64 + rowe;
                int slot = atomicAdd(&cntL[tok], 1);          // LDS: fast return
                if (slot < CAP)                                // fire-and-forget
                    candi[((size_t)ks * N_TOK + n0 + tok) * CAP + slot] =
                        (unsigned short)(cb + cl);
            }
            if (a1[e] > m1[e] - MARGIN_GP) {
                int tok = w * 64 + 32 + rowe;
                int slot = atomicAdd(&cntL[tok], 1);
                if (slot < CAP)
                    candi[((size_t)ks * N_TOK + n0 + tok) * CAP + slot] =
                        (unsigned short)(cb + cl);
            }
        }
    };

    STAGE(0, 0);
    for (int i = 0; i < NBUF; i += 2) {
        __syncthreads();                 // drain: stage(i) landed; buf1 readers done
        STAGE(i + 1, 1);
        COMPUTE(i, 0);
        __syncthreads();                 // drain: stage(i+1) landed; buf0 readers done
        if (i + 2 < NBUF) STAGE(i + 2, 0);
        COMPUTE(i + 1, 1);
    }

    __syncthreads();
    cnt[ks * N_TOK + n0 + t] = cntL[t];  // single flush to global (t covers BM)
}

// ---------------------------------------------------------------------------
// Fused exact rescore + gather. 32 tokens/block. FOUR candidate lists/token.
#define GT 32
__global__ __launch_bounds__(256) void vq_rg_kernel(
    const float* __restrict__ z, const float* __restrict__ emb,
    const float* __restrict__ z2, const int* __restrict__ cnt,
    const unsigned short* __restrict__ candi,
    int* __restrict__ counts, double* __restrict__ mse_sum,
    float* __restrict__ out_zq, float* __restrict__ out_idx)
{
    __shared__ float zs[GT][257];
    __shared__ float zq[GT][DIM];
    __shared__ unsigned long long kmin[GT];
    __shared__ int sidx[GT];
    __shared__ double red[4];
    int t = threadIdx.x;
    int n0 = blockIdx.x * GT;
    int b = n0 >> 10, hw0 = n0 & 1023;
    int lane = t & 63, w = t >> 6;

    {   // coalesced z stage: lanes = hw, groups = c
        int nn = t & 31, cg = t >> 5;
        const float* zb = z + (size_t)b * DIM * HW + hw0 + nn;
        #pragma unroll 4
        for (int i = 0; i < 32; i++) {
            int c = i*8 + cg;
            zs[nn][c] = zb[(size_t)c * HW];
        }
    }
    if (t < GT) kmin[t] = ~0ULL;
    __syncthreads();

    // wave w owns tokens w*8 .. w*8+7 ; 4 lists per token
    int tb1[8], tb2[8], tb3[8], po[9];
    int ovf8 = 0;
    po[0] = 0;
    #pragma unroll
    for (int i = 0; i < 8; i++) {
        int n = n0 + w*8 + i;
        int c0 = cnt[n],             c1 = cnt[N_TOK + n];
        int c2 = cnt[2*N_TOK + n],   c3 = cnt[3*N_TOK + n];
        if (c0 > CAP || c1 > CAP || c2 > CAP || c3 > CAP) {
            c0 = c1 = c2 = c3 = 0; ovf8 |= (1 << i);
        }
        tb1[i] = c0;
        tb2[i] = c0 + c1;
        tb3[i] = c0 + c1 + c2;
        po[i+1] = po[i] + c0 + c1 + c2 + c3;
    }
    int total = po[8];

    for (int base = 0; base < total; base += 64) {
        int g = base + lane;
        unsigned long long key = ~0ULL;
        int mytok = -1;
        if (g < total) {
            int i = 0;
            #pragma unroll
            for (int q = 1; q < 8; q++) i += (g >= po[q]);
            int sl = g - po[i];
            int n = n0 + w*8 + i;
            int s = 0, off = 0;
            if (sl >= tb1[i]) { s = 1; off = tb1[i]; }
            if (sl >= tb2[i]) { s = 2; off = tb2[i]; }
            if (sl >= tb3[i]) { s = 3; off = tb3[i]; }
            int slot = sl - off;
            int code = candi[((size_t)s * N_TOK + n) * CAP + slot];
            int tok = w*8 + i;
            float accv = 0.f;
            const float4* ep = (const float4*)(emb + (size_t)code * DIM);
            #pragma unroll 8
            for (int q4 = 0; q4 < 64; q4++) {
                float4 e4 = ep[q4];
                accv = fmaf(zs[tok][q4*4+0], e4.x, accv);
                accv = fmaf(zs[tok][q4*4+1], e4.y, accv);
                accv = fmaf(zs[tok][q4*4+2], e4.z, accv);
                accv = fmaf(zs[tok][q4*4+3], e4.w, accv);
            }
            float d = fmaf(-2.f, accv, z2[n]);
            key = ((unsigned long long)__float_as_uint(d) << 32) | (unsigned)code;
            mytok = tok;
        }
        #pragma unroll
        for (int i = 0; i < 8; i++) {
            unsigned long long kk = (mytok == w*8 + i) ? key : ~0ULL;
            #pragma unroll
            for (int o = 32; o > 0; o >>= 1) {
                unsigned long long ob = __shfl_xor(kk, o);
                if (ob < kk) kk = ob;
            }
            if (lane == 0 && kk < kmin[w*8 + i]) kmin[w*8 + i] = kk;
        }
    }

    // overflow fallback: full scan (provably correct)
    for (int i = 0; i < 8; i++) if (ovf8 & (1 << i)) {
        int tok = w*8 + i, n = n0 + tok;
        float z2n = z2[n];
        unsigned long long bst = ~0ULL;
        for (int k = lane; k < NUM_EMB; k += 64) {
            float accv = 0.f;
            const float4* ep = (const float4*)(emb + (size_t)k * DIM);
            #pragma unroll 8
            for (int q4 = 0; q4 < 64; q4++) {
                float4 e4 = ep[q4];
                accv = fmaf(zs[tok][q4*4+0], e4.x, accv);
                accv = fmaf(zs[tok][q4*4+1], e4.y, accv);
                accv = fmaf(zs[tok][q4*4+2], e4.z, accv);
                accv = fmaf(zs[tok][q4*4+3], e4.w, accv);
            }
            float d = fmaf(-2.f, accv, z2n);
            unsigned long long kk =
                ((unsigned long long)__float_as_uint(d) << 32) | (unsigned)k;
            if (kk < bst) bst = kk;
        }
        #pragma unroll
        for (int o = 32; o > 0; o >>= 1) {
            unsigned long long ob = __shfl_xor(bst, o);
            if (ob < bst) bst = ob;
        }
        if (lane == 0 && bst < kmin[tok]) kmin[tok] = bst;
    }
    __syncthreads();

    if (t < GT) {
        int bi = (int)(kmin[t] & 0xffffffffu);
        sidx[t] = bi;
        out_idx[n0 + t] = (float)bi;
        atomicAdd(&counts[bi], 1);
    }
    __syncthreads();

    // gather selected emb rows (rotated layout)
    for (int m = w*8; m < w*8 + 8; m++) {
        int row = sidx[m];
        float4 v = *(const float4*)(emb + (size_t)row * DIM + lane * 4);
        int cb = (lane + m) & 63;
        *(float4*)&zq[m][cb * 4] = v;
    }
    __syncthreads();

    int nn = t & 31, cc = t >> 5;
    float* op = out_zq + (size_t)b * DIM * HW + hw0 + nn;
    float lsum = 0.f;
    #pragma unroll 4
    for (int i = 0; i < 32; i++) {
        int c = i*8 + cc;
        int cb = ((c >> 2) + nn) & 63;
        float q = zq[nn][cb*4 + (c & 3)];
        float zv = zs[nn][c];
        op[(size_t)c * HW] = __fadd_rn(zv, __fsub_rn(q, zv));
        float d = zv - q;
        lsum = fmaf(d, d, lsum);
    }
    double ds = (double)lsum;
    #pragma unroll
    for (int off = 32; off > 0; off >>= 1)
        ds += __shfl_down(ds, off);
    if (lane == 0) red[w] = ds;
    __syncthreads();
    if (t == 0) atomicAdd(mse_sum, red[0] + red[1] + red[2] + red[3]);
}

// ---------------------------------------------------------------------------
__global__ __launch_bounds__(256) void vq_finalize_kernel(
    const double* __restrict__ mse_sum, const int* __restrict__ counts,
    float* __restrict__ out_scalars)
{
    __shared__ float red[4];
    int t = threadIdx.x;
    float local = 0.f;
    for (int k = t; k < NUM_EMB; k += 256) {
        int c = counts[k];
        if (c > 0) {
            float p = (float)c * (1.0f / (float)N_TOK);
            local += p * logf(p);
        }
    }
    int lane = t & 63, w = t >> 6;
    #pragma unroll
    for (int off = 32; off > 0; off >>= 1)
        local += __shfl_down(local, off);
    if (lane == 0) red[w] = local;
    __syncthreads();
    if (t == 0) {
        float s = red[0] + red[1] + red[2] + red[3];
        out_scalars[0] = 1.25f * (float)(*mse_sum * (1.0 / (double)OUT_ZQ_ELEMS));
        out_scalars[1] = expf(-s);
    }
}

// ---------------------------------------------------------------------------
extern "C" void kernel_launch(void* const* d_in, const int* in_sizes, int n_in,
                              void* d_out, int out_size, void* d_ws, size_t ws_size,
                              hipStream_t stream)
{
    const float* z   = (const float*)d_in[0];   // [32,256,32,32]
    const float* emb = (const float*)d_in[1];   // [8192,256]
    float* out = (float*)d_out;
    char* ws = (char*)d_ws;
    double* mse_sum = (double*)(ws + WS_MSE);
    int*    counts  = (int*)(ws + WS_COUNTS);
    int*    cnt     = (int*)(ws + WS_CNT);
    float*  z2      = (float*)(ws + WS_Z2);
    unsigned short* candi = (unsigned short*)(ws + WS_CANDI);

    // fp16 packs live in d_out's z_q region, overwritten later by vq_rg_kernel
    _Float16* zh = (_Float16*)d_out;             // 16.78 MB
    _Float16* eh = (_Float16*)(out + 4194304);   //  4.19 MB

    hipMemsetAsync(d_ws, 0, WS_MEMSET_END, stream);

    vq_pack_e<<<NUM_EMB*DIM/4/256, 256, 0, stream>>>(emb, eh);
    vq_pack_z<<<N_TOK/32, 256, 0, stream>>>(z, zh, z2);
    vq_dist_kernel<<<dim3(N_TOK/BM, KSPLIT), 256, 0, stream>>>(zh, eh, cnt, candi);
    vq_rg_kernel<<<N_TOK/GT, 256, 0, stream>>>(z, emb, z2, cnt, candi,
                                               counts, mse_sum,
                                               out, out + OUT_ZQ_ELEMS + 2);
    vq_finalize_kernel<<<1, 256, 0, stream>>>(mse_sum, counts, out + OUT_ZQ_ELEMS);
}

// Round 12
// 735.316 us; speedup vs baseline: 1.5671x; 1.5671x over previous
//
#include <hip/hip_runtime.h>
#include <hip/hip_fp16.h>
#include <cmath>
#include <float.h>

// Problem constants
#define NUM_EMB 8192
#define DIM 256
#define HW 1024
#define N_TOK 32768
#define KSPLIT 4
#define KRANGE (NUM_EMB/KSPLIT)      // 2048 codes per split
#define OUT_ZQ_ELEMS 8388608

// coarse capture: G' = 8192 * z.e ; d-margin = 2*0.4/8192 = 9.8e-5 vs required
// cell(3.05e-5)+2*eps_fp16(2.6e-5) = 5.7e-5 -> 1.7x safety
// capture superset is safe (cut only ever lowered); CAP overflow falls back to
// exact full scan in vq_rg_kernel.
// R12 lesson (from R11): the 256-code reduce window overflowed CAP=24 ->
// rg fallback storm AND dist LDS-atomic serialization (32 lanes share one
// cntL[tok] per e-slot). Cadence MUST stay at the 128-code window that R10
// validated at CAP=24. B-reuse x2 (64-token waves) is kept: DS-reads and
// addressing VALU halved, 2 independent MFMA chains per wave.
#define CAP 24
#define MARGIN_GP 0.4f

// dist tiling: block = 256 tokens x KRANGE codes; LDS buffer = 32 codes (16KB)
#define BM 256
#define BCODES 32
#define NBUF (KRANGE/BCODES)         // 64 buffers per block

// ws layout (byte offsets)
#define WS_MSE    0
#define WS_COUNTS 64
#define WS_CNT    (WS_COUNTS + NUM_EMB*4)        // int[KSPLIT*N_TOK]
#define WS_MEMSET_END (WS_CNT + KSPLIT*N_TOK*4)
#define WS_Z2     WS_MEMSET_END                  // float[N_TOK]
#define WS_CANDI  (WS_Z2 + N_TOK*4)              // ushort[KSPLIT*N_TOK*CAP]

typedef _Float16 half8 __attribute__((ext_vector_type(8)));
typedef _Float16 half4v __attribute__((ext_vector_type(4)));
typedef float f32x16 __attribute__((ext_vector_type(16)));
typedef __attribute__((address_space(3))) void lds_void;
typedef __attribute__((address_space(1))) const void gbl_void;

// ---------------------------------------------------------------------------
// pack z -> fp16 token-major [n][c]  AND  z2[n] (numpy pairwise_sum(256)-exact)
__global__ __launch_bounds__(256) void vq_pack_z(
    const float* __restrict__ z, _Float16* __restrict__ zh, float* __restrict__ z2)
{
    __shared__ float zt[32][257];
    __shared__ float rr[32][16];
    int t = threadIdx.x;
    int n0 = blockIdx.x * 32;
    int b = n0 >> 10, hw0 = n0 & 1023;
    const float* zb = z + (size_t)b * DIM * HW + hw0;
    int tn = t & 31, tc = t >> 5;
    #pragma unroll 4
    for (int it = 0; it < 32; it++) {
        int c = it * 8 + tc;
        zt[tn][c] = zb[(size_t)c * HW + tn];
    }
    __syncthreads();
    int tn2 = t & 31, tj = t >> 5;
    #pragma unroll
    for (int h = 0; h < 2; h++) {
        float v0 = zt[tn2][h*128 + tj];
        float r = __fmul_rn(v0, v0);
        for (int i = 8; i < 128; i += 8) {
            float v = zt[tn2][h*128 + i + tj];
            r = __fadd_rn(r, __fmul_rn(v, v));
        }
        rr[tn2][h*8 + tj] = r;
    }
    int row = t >> 3, seg = t & 7;
    half8 outv[4];
    #pragma unroll
    for (int q = 0; q < 4; q++)
        #pragma unroll
        for (int u = 0; u < 8; u++)
            outv[q][u] = (_Float16)zt[row][seg*32 + q*8 + u];
    half8* dst = (half8*)(zh + (size_t)(n0 + row) * DIM + seg * 32);
    #pragma unroll
    for (int q = 0; q < 4; q++) dst[q] = outv[q];
    __syncthreads();
    if (t < 32) {
        const float* rw = rr[t];
        float h0 = __fadd_rn(__fadd_rn(__fadd_rn(rw[0], rw[1]), __fadd_rn(rw[2], rw[3])),
                             __fadd_rn(__fadd_rn(rw[4], rw[5]), __fadd_rn(rw[6], rw[7])));
        float h1 = __fadd_rn(__fadd_rn(__fadd_rn(rw[8], rw[9]), __fadd_rn(rw[10], rw[11])),
                             __fadd_rn(__fadd_rn(rw[12], rw[13]), __fadd_rn(rw[14], rw[15])));
        z2[n0 + t] = __fadd_rn(h0, h1);
    }
}

// pack e: fp32 -> fp16 prescaled by 8192 (exact pow2; avoids fp16 denormals)
__global__ __launch_bounds__(256) void vq_pack_e(
    const float* __restrict__ emb, _Float16* __restrict__ eh)
{
    int i = blockIdx.x * 256 + threadIdx.x;
    float4 v = ((const float4*)emb)[i];
    half4v h;
    h[0] = (_Float16)(v.x * 8192.0f);
    h[1] = (_Float16)(v.y * 8192.0f);
    h[2] = (_Float16)(v.z * 8192.0f);
    h[3] = (_Float16)(v.w * 8192.0f);
    *(half4v*)(eh + (size_t)i * 4) = h;
}

// ---------------------------------------------------------------------------
// fp16 MFMA coarse pass v11 (= v10 with R10-validated reduce cadence):
//  - grid (128,4) = 512 blocks = 2 independent blocks/CU; 256 threads = 4
//    waves; wave w owns 64 tokens (2 rowgroups; A0/A1 = 128 VGPRs) and reads
//    all 32 codes of each buffer: each ds_read_b128 feeds TWO MFMAs into two
//    INDEPENDENT acc chains (2x ILP; DS-read bytes and addr VALU halved)
//  - B: 32-code buffers (16KB), double-buffered; 33KB LDS/block
//  - drain-synced staging (ONE __syncthreads per buffer; R2 lesson: keeps eh
//    L2-resident); global_load_lds 16B; rotate-by-code swizzle (0 conflicts)
//  - capture counters in LDS (R4); candi fire-and-forget; cnt flushed once;
//    lane-local running max + exact 32-lane reduce every 4th buffer
//    (128-code window, R10-validated at CAP=24), warmup i<4
__global__ __launch_bounds__(256) void vq_dist_kernel(
    const _Float16* __restrict__ zh, const _Float16* __restrict__ eh,
    int* __restrict__ cnt, unsigned short* __restrict__ candi)
{
    __shared__ _Float16 Bs[2][8192];    // 2 x 16KB: 32 codes x 256 k, swizzled
    __shared__ int cntL[BM];            // per-token capture counter (LDS atomic)
    int t = threadIdx.x;
    int w = t >> 6, lane = t & 63;
    int lm = lane & 31, lh = lane >> 5;
    int n0 = blockIdx.x * BM;
    int ks = blockIdx.y;
    int kbase = ks * KRANGE;

    cntL[t] = 0;

    // A fragments: 64 tokens (2 rowgroups of 32), full K=256, zero LDS traffic
    const _Float16* arow = zh + (size_t)(n0 + w*64 + lm) * DIM + lh * 8;
    half8 A0[16], A1[16];
    #pragma unroll
    for (int s = 0; s < 16; s++) {
        A0[s] = *(const half8*)(arow + s * 16);
        A1[s] = *(const half8*)(arow + 32*DIM + s * 16);
    }

    // stage: chunk p = rr*256+t in [0,1024): code=p>>5 (32 codes), slot=p&31,
    // logical oct = ((p&31)-code)&31 (rotate-by-code; conflict-free b128 reads)
    auto STAGE = [&](int ii, int b) {
        int cb0 = kbase + ii * BCODES;
        #pragma unroll
        for (int rr = 0; rr < 4; rr++) {
            int p = rr * 256 + t;
            int cd = p >> 5;
            int oc = ((p & 31) - cd) & 31;
            __builtin_amdgcn_global_load_lds(
                (gbl_void*)(eh + (size_t)(cb0 + cd) * DIM + oc * 8),
                (lds_void*)((char*)&Bs[b][0] + p * 16), 16, 0, 0);
        }
    };

    // lane-local running max per (rowgroup, e); reduced cross-lane periodically
    float m0[16], m1[16];
    #pragma unroll
    for (int e = 0; e < 16; e++) { m0[e] = -1e30f; m1[e] = -1e30f; }

    int cl = lm;                         // this lane's code within 32-code buffer

    auto COMPUTE = [&](int i, int b) {
        const _Float16* Bb = &Bs[b][0] + (size_t)cl * 256;  // 32 octs * 8 halves
        f32x16 a0, a1;
        #pragma unroll
        for (int e = 0; e < 16; e++) { a0[e] = 0.f; a1[e] = 0.f; }

        __builtin_amdgcn_s_setprio(1);
        #pragma unroll
        for (int s = 0; s < 16; s++) {
            half8 bf = *(const half8*)(Bb + (((s*2 + lh) + cl) & 31) * 8);
            a0 = __builtin_amdgcn_mfma_f32_32x32x16_f16(A0[s], bf, a0, 0, 0, 0);
            a1 = __builtin_amdgcn_mfma_f32_32x32x16_f16(A1[s], bf, a1, 0, 0, 0);
        }
        __builtin_amdgcn_s_setprio(0);

        // lane-local max update
        #pragma unroll
        for (int e = 0; e < 16; e++) {
            m0[e] = fmaxf(m0[e], a0[e]);
            m1[e] = fmaxf(m1[e], a1[e]);
        }
        bool doRed = (i < 4) || ((i & 3) == 3);   // 128-code window (R10-proven)
        if (doRed) {  // exact row max across the 32 column-lanes
            #pragma unroll
            for (int e = 0; e < 16; e++) {
                float q0 = m0[e], q1 = m1[e];
                #pragma unroll
                for (int o = 1; o <= 16; o <<= 1) {
                    q0 = fmaxf(q0, __shfl_xor(q0, o));
                    q1 = fmaxf(q1, __shfl_xor(q1, o));
                }
                m0[e] = q0; m1[e] = q1;
            }
        }
        int cb = kbase + i * BCODES;
        #pragma unroll
        for (int e = 0; e < 16; e++) {
            int rowe = (e & 3) + 8 * (e >> 2) + 4 * lh;
            if (a0[e] > m0[e] - MARGIN_GP) {
                int tok = w * 64 + rowe;
                int slot = atomicAdd(&cntL[tok], 1);          // LDS: fast return
                if (slot < CAP)                                // fire-and-forget
                    candi[((size_t)ks * N_TOK + n0 + tok) * CAP + slot] =
                        (unsigned short)(cb + cl);
            }
            if (a1[e] > m1[e] - MARGIN_GP) {
                int tok = w * 64 + 32 + rowe;
                int slot = atomicAdd(&cntL[tok], 1);
                if (slot < CAP)
                    candi[((size_t)ks * N_TOK + n0 + tok) * CAP + slot] =
                        (unsigned short)(cb + cl);
            }
        }
    };

    STAGE(0, 0);
    for (int i = 0; i < NBUF; i += 2) {
        __syncthreads();                 // drain: stage(i) landed; buf1 readers done
        STAGE(i + 1, 1);
        COMPUTE(i, 0);
        __syncthreads();                 // drain: stage(i+1) landed; buf0 readers done
        if (i + 2 < NBUF) STAGE(i + 2, 0);
        COMPUTE(i + 1, 1);
    }

    __syncthreads();
    cnt[ks * N_TOK + n0 + t] = cntL[t];  // single flush to global (t covers BM)
}

// ---------------------------------------------------------------------------
// Fused exact rescore + gather. 32 tokens/block. FOUR candidate lists/token.
#define GT 32
__global__ __launch_bounds__(256) void vq_rg_kernel(
    const float* __restrict__ z, const float* __restrict__ emb,
    const float* __restrict__ z2, const int* __restrict__ cnt,
    const unsigned short* __restrict__ candi,
    int* __restrict__ counts, double* __restrict__ mse_sum,
    float* __restrict__ out_zq, float* __restrict__ out_idx)
{
    __shared__ float zs[GT][257];
    __shared__ float zq[GT][DIM];
    __shared__ unsigned long long kmin[GT];
    __shared__ int sidx[GT];
    __shared__ double red[4];
    int t = threadIdx.x;
    int n0 = blockIdx.x * GT;
    int b = n0 >> 10, hw0 = n0 & 1023;
    int lane = t & 63, w = t >> 6;

    {   // coalesced z stage: lanes = hw, groups = c
        int nn = t & 31, cg = t >> 5;
        const float* zb = z + (size_t)b * DIM * HW + hw0 + nn;
        #pragma unroll 4
        for (int i = 0; i < 32; i++) {
            int c = i*8 + cg;
            zs[nn][c] = zb[(size_t)c * HW];
        }
    }
    if (t < GT) kmin[t] = ~0ULL;
    __syncthreads();

    // wave w owns tokens w*8 .. w*8+7 ; 4 lists per token
    int tb1[8], tb2[8], tb3[8], po[9];
    int ovf8 = 0;
    po[0] = 0;
    #pragma unroll
    for (int i = 0; i < 8; i++) {
        int n = n0 + w*8 + i;
        int c0 = cnt[n],             c1 = cnt[N_TOK + n];
        int c2 = cnt[2*N_TOK + n],   c3 = cnt[3*N_TOK + n];
        if (c0 > CAP || c1 > CAP || c2 > CAP || c3 > CAP) {
            c0 = c1 = c2 = c3 = 0; ovf8 |= (1 << i);
        }
        tb1[i] = c0;
        tb2[i] = c0 + c1;
        tb3[i] = c0 + c1 + c2;
        po[i+1] = po[i] + c0 + c1 + c2 + c3;
    }
    int total = po[8];

    for (int base = 0; base < total; base += 64) {
        int g = base + lane;
        unsigned long long key = ~0ULL;
        int mytok = -1;
        if (g < total) {
            int i = 0;
            #pragma unroll
            for (int q = 1; q < 8; q++) i += (g >= po[q]);
            int sl = g - po[i];
            int n = n0 + w*8 + i;
            int s = 0, off = 0;
            if (sl >= tb1[i]) { s = 1; off = tb1[i]; }
            if (sl >= tb2[i]) { s = 2; off = tb2[i]; }
            if (sl >= tb3[i]) { s = 3; off = tb3[i]; }
            int slot = sl - off;
            int code = candi[((size_t)s * N_TOK + n) * CAP + slot];
            int tok = w*8 + i;
            float accv = 0.f;
            const float4* ep = (const float4*)(emb + (size_t)code * DIM);
            #pragma unroll 8
            for (int q4 = 0; q4 < 64; q4++) {
                float4 e4 = ep[q4];
                accv = fmaf(zs[tok][q4*4+0], e4.x, accv);
                accv = fmaf(zs[tok][q4*4+1], e4.y, accv);
                accv = fmaf(zs[tok][q4*4+2], e4.z, accv);
                accv = fmaf(zs[tok][q4*4+3], e4.w, accv);
            }
            float d = fmaf(-2.f, accv, z2[n]);
            key = ((unsigned long long)__float_as_uint(d) << 32) | (unsigned)code;
            mytok = tok;
        }
        #pragma unroll
        for (int i = 0; i < 8; i++) {
            unsigned long long kk = (mytok == w*8 + i) ? key : ~0ULL;
            #pragma unroll
            for (int o = 32; o > 0; o >>= 1) {
                unsigned long long ob = __shfl_xor(kk, o);
                if (ob < kk) kk = ob;
            }
            if (lane == 0 && kk < kmin[w*8 + i]) kmin[w*8 + i] = kk;
        }
    }

    // overflow fallback: full scan (provably correct)
    for (int i = 0; i < 8; i++) if (ovf8 & (1 << i)) {
        int tok = w*8 + i, n = n0 + tok;
        float z2n = z2[n];
        unsigned long long bst = ~0ULL;
        for (int k = lane; k < NUM_EMB; k += 64) {
            float accv = 0.f;
            const float4* ep = (const float4*)(emb + (size_t)k * DIM);
            #pragma unroll 8
            for (int q4 = 0; q4 < 64; q4++) {
                float4 e4 = ep[q4];
                accv = fmaf(zs[tok][q4*4+0], e4.x, accv);
                accv = fmaf(zs[tok][q4*4+1], e4.y, accv);
                accv = fmaf(zs[tok][q4*4+2], e4.z, accv);
                accv = fmaf(zs[tok][q4*4+3], e4.w, accv);
            }
            float d = fmaf(-2.f, accv, z2n);
            unsigned long long kk =
                ((unsigned long long)__float_as_uint(d) << 32) | (unsigned)k;
            if (kk < bst) bst = kk;
        }
        #pragma unroll
        for (int o = 32; o > 0; o >>= 1) {
            unsigned long long ob = __shfl_xor(bst, o);
            if (ob < bst) bst = ob;
        }
        if (lane == 0 && bst < kmin[tok]) kmin[tok] = bst;
    }
    __syncthreads();

    if (t < GT) {
        int bi = (int)(kmin[t] & 0xffffffffu);
        sidx[t] = bi;
        out_idx[n0 + t] = (float)bi;
        atomicAdd(&counts[bi], 1);
    }
    __syncthreads();

    // gather selected emb rows (rotated layout)
    for (int m = w*8; m < w*8 + 8; m++) {
        int row = sidx[m];
        float4 v = *(const float4*)(emb + (size_t)row * DIM + lane * 4);
        int cb = (lane + m) & 63;
        *(float4*)&zq[m][cb * 4] = v;
    }
    __syncthreads();

    int nn = t & 31, cc = t >> 5;
    float* op = out_zq + (size_t)b * DIM * HW + hw0 + nn;
    float lsum = 0.f;
    #pragma unroll 4
    for (int i = 0; i < 32; i++) {
        int c = i*8 + cc;
        int cb = ((c >> 2) + nn) & 63;
        float q = zq[nn][cb*4 + (c & 3)];
        float zv = zs[nn][c];
        op[(size_t)c * HW] = __fadd_rn(zv, __fsub_rn(q, zv));
        float d = zv - q;
        lsum = fmaf(d, d, lsum);
    }
    double ds = (double)lsum;
    #pragma unroll
    for (int off = 32; off > 0; off >>= 1)
        ds += __shfl_down(ds, off);
    if (lane == 0) red[w] = ds;
    __syncthreads();
    if (t == 0) atomicAdd(mse_sum, red[0] + red[1] + red[2] + red[3]);
}

// ---------------------------------------------------------------------------
__global__ __launch_bounds__(256) void vq_finalize_kernel(
    const double* __restrict__ mse_sum, const int* __restrict__ counts,
    float* __restrict__ out_scalars)
{
    __shared__ float red[4];
    int t = threadIdx.x;
    float local = 0.f;
    for (int k = t; k < NUM_EMB; k += 256) {
        int c = counts[k];
        if (c > 0) {
            float p = (float)c * (1.0f / (float)N_TOK);
            local += p * logf(p);
        }
    }
    int lane = t & 63, w = t >> 6;
    #pragma unroll
    for (int off = 32; off > 0; off >>= 1)
        local += __shfl_down(local, off);
    if (lane == 0) red[w] = local;
    __syncthreads();
    if (t == 0) {
        float s = red[0] + red[1] + red[2] + red[3];
        out_scalars[0] = 1.25f * (float)(*mse_sum * (1.0 / (double)OUT_ZQ_ELEMS));
        out_scalars[1] = expf(-s);
    }
}

// ---------------------------------------------------------------------------
extern "C" void kernel_launch(void* const* d_in, const int* in_sizes, int n_in,
                              void* d_out, int out_size, void* d_ws, size_t ws_size,
                              hipStream_t stream)
{
    const float* z   = (const float*)d_in[0];   // [32,256,32,32]
    const float* emb = (const float*)d_in[1];   // [8192,256]
    float* out = (float*)d_out;
    char* ws = (char*)d_ws;
    double* mse_sum = (double*)(ws + WS_MSE);
    int*    counts  = (int*)(ws + WS_COUNTS);
    int*    cnt     = (int*)(ws + WS_CNT);
    float*  z2      = (float*)(ws + WS_Z2);
    unsigned short* candi = (unsigned short*)(ws + WS_CANDI);

    // fp16 packs live in d_out's z_q region, overwritten later by vq_rg_kernel
    _Float16* zh = (_Float16*)d_out;             // 16.78 MB
    _Float16* eh = (_Float16*)(out + 4194304);   //  4.19 MB

    hipMemsetAsync(d_ws, 0, WS_MEMSET_END, stream);

    vq_pack_e<<<NUM_EMB*DIM/4/256, 256, 0, stream>>>(emb, eh);
    vq_pack_z<<<N_TOK/32, 256, 0, stream>>>(z, zh, z2);
    vq_dist_kernel<<<dim3(N_TOK/BM, KSPLIT), 256, 0, stream>>>(zh, eh, cnt, candi);
    vq_rg_kernel<<<N_TOK/GT, 256, 0, stream>>>(z, emb, z2, cnt, candi,
                                               counts, mse_sum,
                                               out, out + OUT_ZQ_ELEMS + 2);
    vq_finalize_kernel<<<1, 256, 0, stream>>>(mse_sum, counts, out + OUT_ZQ_ELEMS);
}

// Round 13
// 446.937 us; speedup vs baseline: 2.5782x; 1.6452x over previous
//
#include <hip/hip_runtime.h>
#include <hip/hip_fp16.h>
#include <cmath>
#include <float.h>

// Problem constants
#define NUM_EMB 8192
#define DIM 256
#define HW 1024
#define N_TOK 32768
#define OUT_ZQ_ELEMS 8388608

// coarse capture: G' = 8192 * z.e ; d-margin = 2*0.4/8192 = 9.8e-5 vs required
// cell(3.05e-5)+2*eps_fp16(2.6e-5) = 5.7e-5 -> 1.7x safety
// capture superset is safe (cut only ever lowered); CAP overflow falls back to
// exact full scan in vq_rg_kernel.
// R13: dist is converged (~305-311us invariant across R4/R7/R10 structures;
// B-reuse (R12) and occupancy levers (R5/R10) all fail on register/occupancy
// trades). This round reverts to the measured-best R4 config and fixes rg's
// ILP bug: the 1024-deep serial fmaf chain -> 4 component accumulators.
#define CAP 48
#define MARGIN_GP 0.4f

// dist tiling: block = 128 tokens x all 8192 codes; LDS buffer = 64 codes (32KB)
#define BM 128
#define BCODES 64
#define NBUF (NUM_EMB/BCODES)        // 128 buffers per block

// ws layout (byte offsets)
#define WS_MSE    0
#define WS_COUNTS 64
#define WS_CNT    (WS_COUNTS + NUM_EMB*4)        // int[N_TOK]
#define WS_MEMSET_END (WS_CNT + N_TOK*4)
#define WS_Z2     WS_MEMSET_END                  // float[N_TOK]
#define WS_CANDI  (WS_Z2 + N_TOK*4)              // ushort[N_TOK*CAP]

typedef _Float16 half8 __attribute__((ext_vector_type(8)));
typedef _Float16 half4v __attribute__((ext_vector_type(4)));
typedef float f32x16 __attribute__((ext_vector_type(16)));
typedef __attribute__((address_space(3))) void lds_void;
typedef __attribute__((address_space(1))) const void gbl_void;

// ---------------------------------------------------------------------------
// pack z -> fp16 token-major [n][c]  AND  z2[n] (numpy pairwise_sum(256)-exact)
__global__ __launch_bounds__(256) void vq_pack_z(
    const float* __restrict__ z, _Float16* __restrict__ zh, float* __restrict__ z2)
{
    __shared__ float zt[32][257];
    __shared__ float rr[32][16];
    int t = threadIdx.x;
    int n0 = blockIdx.x * 32;
    int b = n0 >> 10, hw0 = n0 & 1023;
    const float* zb = z + (size_t)b * DIM * HW + hw0;
    int tn = t & 31, tc = t >> 5;
    #pragma unroll 4
    for (int it = 0; it < 32; it++) {
        int c = it * 8 + tc;
        zt[tn][c] = zb[(size_t)c * HW + tn];
    }
    __syncthreads();
    int tn2 = t & 31, tj = t >> 5;
    #pragma unroll
    for (int h = 0; h < 2; h++) {
        float v0 = zt[tn2][h*128 + tj];
        float r = __fmul_rn(v0, v0);
        for (int i = 8; i < 128; i += 8) {
            float v = zt[tn2][h*128 + i + tj];
            r = __fadd_rn(r, __fmul_rn(v, v));
        }
        rr[tn2][h*8 + tj] = r;
    }
    int row = t >> 3, seg = t & 7;
    half8 outv[4];
    #pragma unroll
    for (int q = 0; q < 4; q++)
        #pragma unroll
        for (int u = 0; u < 8; u++)
            outv[q][u] = (_Float16)zt[row][seg*32 + q*8 + u];
    half8* dst = (half8*)(zh + (size_t)(n0 + row) * DIM + seg * 32);
    #pragma unroll
    for (int q = 0; q < 4; q++) dst[q] = outv[q];
    __syncthreads();
    if (t < 32) {
        const float* rw = rr[t];
        float h0 = __fadd_rn(__fadd_rn(__fadd_rn(rw[0], rw[1]), __fadd_rn(rw[2], rw[3])),
                             __fadd_rn(__fadd_rn(rw[4], rw[5]), __fadd_rn(rw[6], rw[7])));
        float h1 = __fadd_rn(__fadd_rn(__fadd_rn(rw[8], rw[9]), __fadd_rn(rw[10], rw[11])),
                             __fadd_rn(__fadd_rn(rw[12], rw[13]), __fadd_rn(rw[14], rw[15])));
        z2[n0 + t] = __fadd_rn(h0, h1);
    }
}

// pack e: fp32 -> fp16 prescaled by 8192 (exact pow2; avoids fp16 denormals)
__global__ __launch_bounds__(256) void vq_pack_e(
    const float* __restrict__ emb, _Float16* __restrict__ eh)
{
    int i = blockIdx.x * 256 + threadIdx.x;
    float4 v = ((const float4*)emb)[i];
    half4v h;
    h[0] = (_Float16)(v.x * 8192.0f);
    h[1] = (_Float16)(v.y * 8192.0f);
    h[2] = (_Float16)(v.z * 8192.0f);
    h[3] = (_Float16)(v.w * 8192.0f);
    *(half4v*)(eh + (size_t)i * 4) = h;
}

// ---------------------------------------------------------------------------
// fp16 MFMA coarse pass (R4 config verbatim -- measured best: 311us):
//  - 256 blocks (1/CU), 512 threads = 8 waves: wave (r,c): r = token rowgroup
//    (32 tokens, A in 64 VGPRs), c = 32-code half of the 64-code buffer
//  - B: 64-code buffers (32KB), double-buffered (64KB LDS), global_load_lds 16B,
//    rotate-by-code swizzle (conflict-free b128 reads)
//  - ONE __syncthreads per buffer (drain keeps eh L2-resident; R2 lesson)
//  - capture slot counters in LDS (R4 lesson: global blocking atomics were the
//    hidden serial cost); candi store fire-and-forget; cnt flushed once
//  - c-waves share per-token running max via LDS mailbox mx[2][BM]; monotone
//    -> lagged/torn read is a valid lower bound -> capture superset -> safe
__global__ __launch_bounds__(512) void vq_dist_kernel(
    const _Float16* __restrict__ zh, const _Float16* __restrict__ eh,
    int* __restrict__ cnt, unsigned short* __restrict__ candi)
{
    __shared__ _Float16 Bs[2][16384];   // 2 x 32KB: 64 codes x 256 k, swizzled
    __shared__ float mx[2][BM];         // per-(c-wave, token) reduced running max
    __shared__ int cntL[BM];            // per-token capture counter (LDS atomic)
    int t = threadIdx.x;
    int w = t >> 6, lane = t & 63;
    int lm = lane & 31, lh = lane >> 5;
    int r = w >> 1, c = w & 1;          // r: token rowgroup (0..3), c: code half
    int n0 = blockIdx.x * BM;

    if (t < BM) {
        cntL[t] = 0;
        mx[0][t] = -1e30f;
        mx[1][t] = -1e30f;
    }

    // A fragments: 32 tokens, full K=256, zero LDS traffic for A
    const _Float16* arow = zh + (size_t)(n0 + r*32 + lm) * DIM + lh * 8;
    half8 A[16];
    #pragma unroll
    for (int s = 0; s < 16; s++)
        A[s] = *(const half8*)(arow + s * 16);

    // stage: chunk p = rr*512+t in [0,2048): code=p>>5 (64 codes), oct slot=p&31,
    // logical oct = ((p&31)-code)&31 (rotate-by-code)
    auto STAGE = [&](int ii, int b) {
        int cb0 = ii * BCODES;
        #pragma unroll
        for (int rr = 0; rr < 4; rr++) {
            int p = rr * 512 + t;
            int cd = p >> 5;
            int oc = ((p & 31) - cd) & 31;
            __builtin_amdgcn_global_load_lds(
                (gbl_void*)(eh + (size_t)(cb0 + cd) * DIM + oc * 8),
                (lds_void*)((char*)&Bs[b][0] + p * 16), 16, 0, 0);
        }
    };

    // lane-local running max per e; reduced cross-lane periodically
    float m[16];
    #pragma unroll
    for (int e = 0; e < 16; e++) m[e] = -1e30f;

    int cl = c * 32 + lm;               // this lane's code within buffer

    auto COMPUTE = [&](int i, int b) {
        // merge sibling c-wave's published max (monotone -> lag-safe)
        #pragma unroll
        for (int e = 0; e < 16; e++) {
            int rowe = (e & 3) + 8 * (e >> 2) + 4 * lh;
            m[e] = fmaxf(m[e], mx[c ^ 1][r * 32 + rowe]);
        }

        const _Float16* Bb = &Bs[b][0] + (size_t)cl * 256;  // 32 octs * 8 halves
        f32x16 acc;
        #pragma unroll
        for (int e = 0; e < 16; e++) acc[e] = 0.f;

        __builtin_amdgcn_s_setprio(1);
        #pragma unroll
        for (int s = 0; s < 16; s++) {
            half8 bf = *(const half8*)(Bb + (((s*2 + lh) + cl) & 31) * 8);
            acc = __builtin_amdgcn_mfma_f32_32x32x16_f16(A[s], bf, acc, 0, 0, 0);
        }
        __builtin_amdgcn_s_setprio(0);

        // lane-local max update
        #pragma unroll
        for (int e = 0; e < 16; e++) m[e] = fmaxf(m[e], acc[e]);
        bool doRed = (i < 4) || ((i & 3) == 3);
        if (doRed) {  // exact row max across the 32 col-lanes; publish to mailbox
            #pragma unroll
            for (int e = 0; e < 16; e++) {
                float q = m[e];
                #pragma unroll
                for (int o = 1; o <= 16; o <<= 1) q = fmaxf(q, __shfl_xor(q, o));
                m[e] = q;
                if (lm == 0) {
                    int rowe = (e & 3) + 8 * (e >> 2) + 4 * lh;
                    mx[c][r * 32 + rowe] = q;
                }
            }
        }
        int cb = i * BCODES;
        #pragma unroll
        for (int e = 0; e < 16; e++) {
            if (acc[e] > m[e] - MARGIN_GP) {
                int rowe = (e & 3) + 8 * (e >> 2) + 4 * lh;
                int tok = r * 32 + rowe;
                int slot = atomicAdd(&cntL[tok], 1);          // LDS: fast return
                if (slot < CAP)                                // fire-and-forget
                    candi[(size_t)(n0 + tok) * CAP + slot] = (unsigned short)(cb + cl);
            }
        }
    };

    STAGE(0, 0);
    for (int i = 0; i < NBUF; i += 2) {
        __syncthreads();                 // drain: stage(i) landed; buf1 readers done
        STAGE(i + 1, 1);
        COMPUTE(i, 0);
        __syncthreads();                 // drain: stage(i+1) landed; buf0 readers done
        if (i + 2 < NBUF) STAGE(i + 2, 0);
        COMPUTE(i + 1, 1);
    }

    __syncthreads();
    if (t < BM) cnt[n0 + t] = cntL[t];   // single flush to global
}

// ---------------------------------------------------------------------------
// Fused exact rescore + gather. 32 tokens/block. Single candidate list/token.
// R13: dot product uses 4 COMPONENT accumulators (ax,ay,az,aw) -- breaks the
// 1024-deep serial fmaf chain into 4x 64-deep chains (4x ILP, loads overlap).
// Reassociation delta (~few ulp over 256 fp32 terms) << the serial-vs-XLA
// delta already tolerated at absmax 0; code-index tiebreak unchanged.
#define GT 32
__global__ __launch_bounds__(256) void vq_rg_kernel(
    const float* __restrict__ z, const float* __restrict__ emb,
    const float* __restrict__ z2, const int* __restrict__ cnt,
    const unsigned short* __restrict__ candi,
    int* __restrict__ counts, double* __restrict__ mse_sum,
    float* __restrict__ out_zq, float* __restrict__ out_idx)
{
    __shared__ float zs[GT][257];
    __shared__ float zq[GT][DIM];
    __shared__ unsigned long long kmin[GT];
    __shared__ int sidx[GT];
    __shared__ double red[4];
    int t = threadIdx.x;
    int n0 = blockIdx.x * GT;
    int b = n0 >> 10, hw0 = n0 & 1023;
    int lane = t & 63, w = t >> 6;

    {   // coalesced z stage: lanes = hw, groups = c
        int nn = t & 31, cg = t >> 5;
        const float* zb = z + (size_t)b * DIM * HW + hw0 + nn;
        #pragma unroll 4
        for (int i = 0; i < 32; i++) {
            int c = i*8 + cg;
            zs[nn][c] = zb[(size_t)c * HW];
        }
    }
    if (t < GT) kmin[t] = ~0ULL;
    __syncthreads();

    // wave w owns tokens w*8 .. w*8+7
    int tc[8], po[9];
    int ovf8 = 0;
    po[0] = 0;
    #pragma unroll
    for (int i = 0; i < 8; i++) {
        int n = n0 + w*8 + i;
        int c0 = cnt[n];
        if (c0 > CAP) { c0 = 0; ovf8 |= (1 << i); }
        tc[i] = c0;
        po[i+1] = po[i] + c0;
    }
    int total = po[8];

    for (int base = 0; base < total; base += 64) {
        int g = base + lane;
        unsigned long long key = ~0ULL;
        int mytok = -1;
        if (g < total) {
            int i = 0;
            #pragma unroll
            for (int q = 1; q < 8; q++) i += (g >= po[q]);
            int sl = g - po[i];
            int n = n0 + w*8 + i;
            int code = candi[(size_t)n * CAP + sl];
            int tok = w*8 + i;
            float ax = 0.f, ay = 0.f, az = 0.f, aw2 = 0.f;
            const float4* ep = (const float4*)(emb + (size_t)code * DIM);
            #pragma unroll 8
            for (int q4 = 0; q4 < 64; q4++) {
                float4 e4 = ep[q4];
                ax  = fmaf(zs[tok][q4*4+0], e4.x, ax);
                ay  = fmaf(zs[tok][q4*4+1], e4.y, ay);
                az  = fmaf(zs[tok][q4*4+2], e4.z, az);
                aw2 = fmaf(zs[tok][q4*4+3], e4.w, aw2);
            }
            float accv = __fadd_rn(__fadd_rn(ax, ay), __fadd_rn(az, aw2));
            float d = fmaf(-2.f, accv, z2[n]);
            key = ((unsigned long long)__float_as_uint(d) << 32) | (unsigned)code;
            mytok = tok;
        }
        #pragma unroll
        for (int i = 0; i < 8; i++) {
            unsigned long long kk = (mytok == w*8 + i) ? key : ~0ULL;
            #pragma unroll
            for (int o = 32; o > 0; o >>= 1) {
                unsigned long long ob = __shfl_xor(kk, o);
                if (ob < kk) kk = ob;
            }
            if (lane == 0 && kk < kmin[w*8 + i]) kmin[w*8 + i] = kk;
        }
    }

    // overflow fallback: full scan (provably correct; same 4-acc dot)
    for (int i = 0; i < 8; i++) if (ovf8 & (1 << i)) {
        int tok = w*8 + i, n = n0 + tok;
        float z2n = z2[n];
        unsigned long long bst = ~0ULL;
        for (int k = lane; k < NUM_EMB; k += 64) {
            float ax = 0.f, ay = 0.f, az = 0.f, aw2 = 0.f;
            const float4* ep = (const float4*)(emb + (size_t)k * DIM);
            #pragma unroll 8
            for (int q4 = 0; q4 < 64; q4++) {
                float4 e4 = ep[q4];
                ax  = fmaf(zs[tok][q4*4+0], e4.x, ax);
                ay  = fmaf(zs[tok][q4*4+1], e4.y, ay);
                az  = fmaf(zs[tok][q4*4+2], e4.z, az);
                aw2 = fmaf(zs[tok][q4*4+3], e4.w, aw2);
            }
            float accv = __fadd_rn(__fadd_rn(ax, ay), __fadd_rn(az, aw2));
            float d = fmaf(-2.f, accv, z2n);
            unsigned long long kk =
                ((unsigned long long)__float_as_uint(d) << 32) | (unsigned)k;
            if (kk < bst) bst = kk;
        }
        #pragma unroll
        for (int o = 32; o > 0; o >>= 1) {
            unsigned long long ob = __shfl_xor(bst, o);
            if (ob < bst) bst = ob;
        }
        if (lane == 0 && bst < kmin[tok]) kmin[tok] = bst;
    }
    __syncthreads();

    if (t < GT) {
        int bi = (int)(kmin[t] & 0xffffffffu);
        sidx[t] = bi;
        out_idx[n0 + t] = (float)bi;
        atomicAdd(&counts[bi], 1);
    }
    __syncthreads();

    // gather selected emb rows (rotated layout)
    for (int m = w*8; m < w*8 + 8; m++) {
        int row = sidx[m];
        float4 v = *(const float4*)(emb + (size_t)row * DIM + lane * 4);
        int cb = (lane + m) & 63;
        *(float4*)&zq[m][cb * 4] = v;
    }
    __syncthreads();

    int nn = t & 31, cc = t >> 5;
    float* op = out_zq + (size_t)b * DIM * HW + hw0 + nn;
    float lsum = 0.f;
    #pragma unroll 4
    for (int i = 0; i < 32; i++) {
        int c = i*8 + cc;
        int cb = ((c >> 2) + nn) & 63;
        float q = zq[nn][cb*4 + (c & 3)];
        float zv = zs[nn][c];
        op[(size_t)c * HW] = __fadd_rn(zv, __fsub_rn(q, zv));
        float d = zv - q;
        lsum = fmaf(d, d, lsum);
    }
    double ds = (double)lsum;
    #pragma unroll
    for (int off = 32; off > 0; off >>= 1)
        ds += __shfl_down(ds, off);
    if (lane == 0) red[w] = ds;
    __syncthreads();
    if (t == 0) atomicAdd(mse_sum, red[0] + red[1] + red[2] + red[3]);
}

// ---------------------------------------------------------------------------
__global__ __launch_bounds__(256) void vq_finalize_kernel(
    const double* __restrict__ mse_sum, const int* __restrict__ counts,
    float* __restrict__ out_scalars)
{
    __shared__ float red[4];
    int t = threadIdx.x;
    float local = 0.f;
    for (int k = t; k < NUM_EMB; k += 256) {
        int c = counts[k];
        if (c > 0) {
            float p = (float)c * (1.0f / (float)N_TOK);
            local += p * logf(p);
        }
    }
    int lane = t & 63, w = t >> 6;
    #pragma unroll
    for (int off = 32; off > 0; off >>= 1)
        local += __shfl_down(local, off);
    if (lane == 0) red[w] = local;
    __syncthreads();
    if (t == 0) {
        float s = red[0] + red[1] + red[2] + red[3];
        out_scalars[0] = 1.25f * (float)(*mse_sum * (1.0 / (double)OUT_ZQ_ELEMS));
        out_scalars[1] = expf(-s);
    }
}

// ---------------------------------------------------------------------------
extern "C" void kernel_launch(void* const* d_in, const int* in_sizes, int n_in,
                              void* d_out, int out_size, void* d_ws, size_t ws_size,
                              hipStream_t stream)
{
    const float* z   = (const float*)d_in[0];   // [32,256,32,32]
    const float* emb = (const float*)d_in[1];   // [8192,256]
    float* out = (float*)d_out;
    char* ws = (char*)d_ws;
    double* mse_sum = (double*)(ws + WS_MSE);
    int*    counts  = (int*)(ws + WS_COUNTS);
    int*    cnt     = (int*)(ws + WS_CNT);
    float*  z2      = (float*)(ws + WS_Z2);
    unsigned short* candi = (unsigned short*)(ws + WS_CANDI);

    // fp16 packs live in d_out's z_q region, overwritten later by vq_rg_kernel
    _Float16* zh = (_Float16*)d_out;             // 16.78 MB
    _Float16* eh = (_Float16*)(out + 4194304);   //  4.19 MB

    hipMemsetAsync(d_ws, 0, WS_MEMSET_END, stream);

    vq_pack_e<<<NUM_EMB*DIM/4/256, 256, 0, stream>>>(emb, eh);
    vq_pack_z<<<N_TOK/32, 256, 0, stream>>>(z, zh, z2);
    vq_dist_kernel<<<N_TOK/BM, 512, 0, stream>>>(zh, eh, cnt, candi);
    vq_rg_kernel<<<N_TOK/GT, 256, 0, stream>>>(z, emb, z2, cnt, candi,
                                               counts, mse_sum,
                                               out, out + OUT_ZQ_ELEMS + 2);
    vq_finalize_kernel<<<1, 256, 0, stream>>>(mse_sum, counts, out + OUT_ZQ_ELEMS);
}